// Round 2
// baseline (2410.267 us; speedup 1.0000x reference)
//
#include <hip/hip_runtime.h>

constexpr int NSRC = 50000;
constexpr int NTGT = 10000;
constexpr int NEDGE = 250000;
constexpr int NLBL = 200000;
constexpr int HD = 64;     // hidden dim (per head)
constexpr int NH = 4;      // heads
constexpr int QK = 256;    // HD*NH
constexpr int NPB = 8;     // nodes per block in projection kernels

// ---------------- CSR build helpers ----------------

__global__ __launch_bounds__(256) void zero_int_kernel(int* p, int n) {
  int i = blockIdx.x * 256 + threadIdx.x;
  if (i < n) p[i] = 0;
}

__global__ __launch_bounds__(256) void copy_int_kernel(const int* __restrict__ a, int* __restrict__ b, int n) {
  int i = blockIdx.x * 256 + threadIdx.x;
  if (i < n) b[i] = a[i];
}

__global__ __launch_bounds__(256) void hist_kernel(const int* __restrict__ dst, int* __restrict__ counts, int n) {
  int i = blockIdx.x * 256 + threadIdx.x;
  if (i < n) atomicAdd(&counts[dst[i]], 1);
}

// single-block exclusive scan: rowptr[0]=0, rowptr[i+1]=sum(counts[0..i])
__global__ __launch_bounds__(1024) void scan_kernel(const int* __restrict__ counts, int* __restrict__ rowptr, int n) {
  __shared__ int sh[1024];
  int t = threadIdx.x;
  int running = 0;
  if (t == 0) rowptr[0] = 0;
  for (int base = 0; base < n; base += 1024) {
    int v = (base + t < n) ? counts[base + t] : 0;
    sh[t] = v;
    __syncthreads();
    for (int off = 1; off < 1024; off <<= 1) {
      int add = (t >= off) ? sh[t - off] : 0;
      __syncthreads();
      sh[t] += add;
      __syncthreads();
    }
    if (base + t < n) rowptr[base + t + 1] = running + sh[t];
    running += sh[1023];
    __syncthreads();
  }
}

// stores SOURCE node id into the slot (that's all aggregation needs)
__global__ __launch_bounds__(256) void scatter_kernel(const int* __restrict__ src, const int* __restrict__ dst,
                                                      int* __restrict__ cursor, int* __restrict__ eids, int n) {
  int i = blockIdx.x * 256 + threadIdx.x;
  if (i < n) {
    int p = atomicAdd(&cursor[dst[i]], 1);
    eids[p] = src[i];
  }
}

// ---------------- init / projections ----------------

__global__ __launch_bounds__(256) void gather_kernel(const float* __restrict__ emb, const int* __restrict__ ids,
                                                     float* __restrict__ out, int n) {
  int i = blockIdx.x * 256 + threadIdx.x;
  if (i < n * HD) out[i] = emb[(size_t)ids[i >> 6] * HD + (i & 63)];
}

// out1 = x@W1+b1, out2 = x@W2+b2 for NPB nodes per block; 256 threads = output col
__global__ __launch_bounds__(256) void proj2_kernel(const float* __restrict__ x,
    const float* __restrict__ W1, const float* __restrict__ b1,
    const float* __restrict__ W2, const float* __restrict__ b2,
    float* __restrict__ o1, float* __restrict__ o2, int N) {
  int base = blockIdx.x * NPB;
  int t = threadIdx.x;
  __shared__ float xs[NPB][HD];
  for (int idx = t; idx < NPB * HD; idx += 256) {
    int n = idx >> 6;
    xs[n][idx & 63] = (base + n < N) ? x[(size_t)(base + n) * HD + (idx & 63)] : 0.f;
  }
  __syncthreads();
  float a1[NPB], a2[NPB];
  float bb1 = b1[t], bb2 = b2[t];
#pragma unroll
  for (int n = 0; n < NPB; ++n) { a1[n] = bb1; a2[n] = bb2; }
#pragma unroll
  for (int i4 = 0; i4 < HD / 4; ++i4) {
    float4 xv[NPB];
#pragma unroll
    for (int n = 0; n < NPB; ++n) xv[n] = ((const float4*)xs[n])[i4];
#pragma unroll
    for (int j = 0; j < 4; ++j) {
      float w1 = W1[(i4 * 4 + j) * QK + t];
      float w2 = W2[(i4 * 4 + j) * QK + t];
#pragma unroll
      for (int n = 0; n < NPB; ++n) {
        float xi = (j == 0) ? xv[n].x : (j == 1) ? xv[n].y : (j == 2) ? xv[n].z : xv[n].w;
        a1[n] = fmaf(xi, w1, a1[n]);
        a2[n] = fmaf(xi, w2, a2[n]);
      }
    }
  }
#pragma unroll
  for (int n = 0; n < NPB; ++n) {
    if (base + n < N) {
      o1[(size_t)(base + n) * QK + t] = a1[n];
      o2[(size_t)(base + n) * QK + t] = a2[n];
    }
  }
}

__global__ __launch_bounds__(256) void proj1_kernel(const float* __restrict__ x,
    const float* __restrict__ W1, const float* __restrict__ b1,
    float* __restrict__ o1, int N) {
  int base = blockIdx.x * NPB;
  int t = threadIdx.x;
  __shared__ float xs[NPB][HD];
  for (int idx = t; idx < NPB * HD; idx += 256) {
    int n = idx >> 6;
    xs[n][idx & 63] = (base + n < N) ? x[(size_t)(base + n) * HD + (idx & 63)] : 0.f;
  }
  __syncthreads();
  float a1[NPB];
  float bb1 = b1[t];
#pragma unroll
  for (int n = 0; n < NPB; ++n) a1[n] = bb1;
#pragma unroll
  for (int i4 = 0; i4 < HD / 4; ++i4) {
    float4 xv[NPB];
#pragma unroll
    for (int n = 0; n < NPB; ++n) xv[n] = ((const float4*)xs[n])[i4];
#pragma unroll
    for (int j = 0; j < 4; ++j) {
      float w1 = W1[(i4 * 4 + j) * QK + t];
#pragma unroll
      for (int n = 0; n < NPB; ++n) {
        float xi = (j == 0) ? xv[n].x : (j == 1) ? xv[n].y : (j == 2) ? xv[n].z : xv[n].w;
        a1[n] = fmaf(xi, w1, a1[n]);
      }
    }
  }
#pragma unroll
  for (int n = 0; n < NPB; ++n)
    if (base + n < N) o1[(size_t)(base + n) * QK + t] = a1[n];
}

// ---------------- attention aggregation ----------------
// one block per destination node; wave h handles head h; lane = feature dim.
// online softmax over in-edges via CSR; epilogue fuses head-mean + skip GEMV + bias + relu.
__global__ __launch_bounds__(256) void agg_kernel(const float* __restrict__ q, const float* __restrict__ k,
    const float* __restrict__ v, const int* __restrict__ rowptr, const int* __restrict__ eids,
    const float* __restrict__ xd_in, const float* __restrict__ Wsk, const float* __restrict__ bsk,
    float* __restrict__ xout, int relu) {
  int node = blockIdx.x;
  int t = threadIdx.x;
  int h = t >> 6, lane = t & 63;
  __shared__ float xd[HD];
  __shared__ float headout[NH][HD];
  if (t < HD) xd[t] = xd_in[(size_t)node * HD + t];
  float qv = q[(size_t)node * QK + h * HD + lane];
  int beg = rowptr[node], end = rowptr[node + 1];
  float m = -1e30f, lsum = 0.f, acc = 0.f;
  for (int e = beg; e < end; ++e) {
    int src = eids[e];
    float kk = k[(size_t)src * QK + h * HD + lane];
    float vv = v[(size_t)src * QK + h * HD + lane];
    float s = qv * kk;
#pragma unroll
    for (int o = 32; o > 0; o >>= 1) s += __shfl_xor(s, o, 64);
    s *= 0.125f;  // 1/sqrt(64)
    float mn = fmaxf(m, s);
    float sc = __expf(m - mn);
    float w = __expf(s - mn);
    lsum = lsum * sc + w;
    acc = acc * sc + w * vv;
    m = mn;
  }
  headout[h][lane] = (lsum > 0.f) ? acc / lsum : 0.f;
  __syncthreads();
  if (t < HD) {
    float r = 0.25f * (headout[0][t] + headout[1][t] + headout[2][t] + headout[3][t]);
    float sk = bsk[t];
#pragma unroll
    for (int i = 0; i < HD; ++i) sk = fmaf(xd[i], Wsk[i * HD + t], sk);
    r += sk;
    if (relu) r = fmaxf(r, 0.f);
    xout[(size_t)node * HD + t] = r;
  }
}

// ---------------- classifier ----------------
__global__ __launch_bounds__(256) void classifier_kernel(const float* __restrict__ xs, const float* __restrict__ xt,
    const int* __restrict__ ls, const int* __restrict__ lt, float* __restrict__ out, int n) {
  int g = blockIdx.x * 256 + threadIdx.x;
  int w = g >> 6, lane = g & 63;
  if (w >= n) return;
  float a = xs[(size_t)ls[w] * HD + lane] * xt[(size_t)lt[w] * HD + lane];
#pragma unroll
  for (int o = 32; o > 0; o >>= 1) a += __shfl_xor(a, o, 64);
  if (lane == 0) out[w] = a;
}

// ---------------- launch ----------------
extern "C" void kernel_launch(void* const* d_in, const int* in_sizes, int n_in,
                              void* d_out, int out_size, void* d_ws, size_t ws_size,
                              hipStream_t stream) {
  const float* src_emb = (const float*)d_in[0];
  const float* tgt_emb = (const float*)d_in[1];
  const float* Wq = (const float*)d_in[2];
  const float* bq = (const float*)d_in[3];
  const float* Wk = (const float*)d_in[4];
  const float* bk = (const float*)d_in[5];
  const float* Wv = (const float*)d_in[6];
  const float* bv = (const float*)d_in[7];
  const float* Wsk = (const float*)d_in[8];
  const float* bsk = (const float*)d_in[9];
  const int* nid_s = (const int*)d_in[10];
  const int* nid_t = (const int*)d_in[11];
  const int* e_st = (const int*)d_in[12];
  const int* e_ts = (const int*)d_in[13];
  const int* e_lbl = (const int*)d_in[14];
  float* out = (float*)d_out;

  char* ws = (char*)d_ws;
  size_t off = 0;
  auto alloc = [&](size_t bytes) -> void* {
    void* p = ws + off;
    off += (bytes + 255) & ~(size_t)255;
    return p;
  };
  // big buffers sized for NSRC nodes, small for NTGT nodes (reused across convs)
  float* big1   = (float*)alloc((size_t)NSRC * QK * 4);   // st: k | ts: q
  float* big2   = (float*)alloc((size_t)NSRC * QK * 4);   // st: v
  float* small1 = (float*)alloc((size_t)NTGT * QK * 4);   // st: q | ts: k
  float* small2 = (float*)alloc((size_t)NTGT * QK * 4);   // ts: v
  float* xsA = (float*)alloc((size_t)NSRC * HD * 4);
  float* xsB = (float*)alloc((size_t)NSRC * HD * 4);
  float* xtA = (float*)alloc((size_t)NTGT * HD * 4);
  float* xtB = (float*)alloc((size_t)NTGT * HD * 4);
  int* rp_st = (int*)alloc((size_t)(NTGT + 1) * 4);
  int* ei_st = (int*)alloc((size_t)NEDGE * 4);
  int* rp_ts = (int*)alloc((size_t)(NSRC + 1) * 4);
  int* ei_ts = (int*)alloc((size_t)NEDGE * 4);
  int* cursor = (int*)alloc((size_t)(NSRC + 1) * 4);
  int* counts = (int*)alloc((size_t)(NSRC + 1) * 4);
  (void)ws_size; (void)in_sizes; (void)n_in; (void)out_size;

  auto cdiv = [](int a, int b) { return (a + b - 1) / b; };

  // CSR st: segment by target (row1 of e_st), payload = source id (row0)
  zero_int_kernel<<<cdiv(NTGT, 256), 256, 0, stream>>>(counts, NTGT);
  hist_kernel<<<cdiv(NEDGE, 256), 256, 0, stream>>>(e_st + NEDGE, counts, NEDGE);
  scan_kernel<<<1, 1024, 0, stream>>>(counts, rp_st, NTGT);
  copy_int_kernel<<<cdiv(NTGT, 256), 256, 0, stream>>>(rp_st, cursor, NTGT);
  scatter_kernel<<<cdiv(NEDGE, 256), 256, 0, stream>>>(e_st, e_st + NEDGE, cursor, ei_st, NEDGE);

  // CSR ts: segment by source node (row1 of e_ts), payload = target id (row0)
  zero_int_kernel<<<cdiv(NSRC, 256), 256, 0, stream>>>(counts, NSRC);
  hist_kernel<<<cdiv(NEDGE, 256), 256, 0, stream>>>(e_ts + NEDGE, counts, NEDGE);
  scan_kernel<<<1, 1024, 0, stream>>>(counts, rp_ts, NSRC);
  copy_int_kernel<<<cdiv(NSRC, 256), 256, 0, stream>>>(rp_ts, cursor, NSRC);
  scatter_kernel<<<cdiv(NEDGE, 256), 256, 0, stream>>>(e_ts, e_ts + NEDGE, cursor, ei_ts, NEDGE);

  // initial node features (node_id_* are identity by construction, but honor semantics)
  gather_kernel<<<cdiv(NSRC * HD, 256), 256, 0, stream>>>(src_emb, nid_s, xsA, NSRC);
  gather_kernel<<<cdiv(NTGT * HD, 256), 256, 0, stream>>>(tgt_emb, nid_t, xtA, NTGT);

  const float* xs_cur = xsA; float* xs_nxt = xsB;
  const float* xt_cur = xtA; float* xt_nxt = xtB;
  for (int l = 0; l < 2; ++l) {
    int relu = (l == 0) ? 1 : 0;
    {  // source->target conv (et=0): updates target nodes
      int p = l * 2 + 0;
      proj2_kernel<<<cdiv(NSRC, NPB), 256, 0, stream>>>(xs_cur, Wk + p * 16384, bk + p * 256,
                                                        Wv + p * 16384, bv + p * 256, big1, big2, NSRC);
      proj1_kernel<<<cdiv(NTGT, NPB), 256, 0, stream>>>(xt_cur, Wq + p * 16384, bq + p * 256, small1, NTGT);
      agg_kernel<<<NTGT, 256, 0, stream>>>(small1, big1, big2, rp_st, ei_st, xt_cur,
                                           Wsk + p * 4096, bsk + p * 64, xt_nxt, relu);
    }
    {  // target->source conv (et=1): updates source nodes
      int p = l * 2 + 1;
      proj2_kernel<<<cdiv(NTGT, NPB), 256, 0, stream>>>(xt_cur, Wk + p * 16384, bk + p * 256,
                                                        Wv + p * 16384, bv + p * 256, small1, small2, NTGT);
      proj1_kernel<<<cdiv(NSRC, NPB), 256, 0, stream>>>(xs_cur, Wq + p * 16384, bq + p * 256, big1, NSRC);
      agg_kernel<<<NSRC, 256, 0, stream>>>(big1, small1, small2, rp_ts, ei_ts, xs_cur,
                                           Wsk + p * 4096, bsk + p * 64, xs_nxt, relu);
    }
    const float* t0 = xs_nxt; xs_nxt = (float*)xs_cur; xs_cur = t0;
    const float* t1 = xt_nxt; xt_nxt = (float*)xt_cur; xt_cur = t1;
  }

  classifier_kernel<<<cdiv(NLBL, 4), 256, 0, stream>>>(xs_cur, xt_cur, e_lbl, e_lbl + NLBL, out, NLBL);
}

// Round 4
// 959.744 us; speedup vs baseline: 2.5114x; 2.5114x over previous
//
#include <hip/hip_runtime.h>

constexpr int NSRC = 50000;
constexpr int NTGT = 10000;
constexpr int NEDGE = 250000;
constexpr int NLBL = 200000;
constexpr int HD = 64;     // hidden dim (per head)
constexpr int NH = 4;      // heads
constexpr int QK = 256;    // HD*NH

// ---------------- CSR build helpers ----------------

__global__ __launch_bounds__(256) void zero_int_kernel(int* p, int n) {
  int i = blockIdx.x * 256 + threadIdx.x;
  if (i < n) p[i] = 0;
}

__global__ __launch_bounds__(256) void copy_int_kernel(const int* __restrict__ a, int* __restrict__ b, int n) {
  int i = blockIdx.x * 256 + threadIdx.x;
  if (i < n) b[i] = a[i];
}

__global__ __launch_bounds__(256) void hist_kernel(const int* __restrict__ dst, int* __restrict__ counts, int n) {
  int i = blockIdx.x * 256 + threadIdx.x;
  if (i < n) atomicAdd(&counts[dst[i]], 1);
}

// single-block exclusive scan: rowptr[0]=0, rowptr[i+1]=sum(counts[0..i])
__global__ __launch_bounds__(1024) void scan_kernel(const int* __restrict__ counts, int* __restrict__ rowptr, int n) {
  __shared__ int sh[1024];
  int t = threadIdx.x;
  int running = 0;
  if (t == 0) rowptr[0] = 0;
  for (int base = 0; base < n; base += 1024) {
    int v = (base + t < n) ? counts[base + t] : 0;
    sh[t] = v;
    __syncthreads();
    for (int off = 1; off < 1024; off <<= 1) {
      int add = (t >= off) ? sh[t - off] : 0;
      __syncthreads();
      sh[t] += add;
      __syncthreads();
    }
    if (base + t < n) rowptr[base + t + 1] = running + sh[t];
    running += sh[1023];
    __syncthreads();
  }
}

// stores SOURCE node id into the slot (that's all aggregation needs)
__global__ __launch_bounds__(256) void scatter_kernel(const int* __restrict__ src, const int* __restrict__ dst,
                                                      int* __restrict__ cursor, int* __restrict__ eids, int n) {
  int i = blockIdx.x * 256 + threadIdx.x;
  if (i < n) {
    int p = atomicAdd(&cursor[dst[i]], 1);
    eids[p] = src[i];
  }
}

// ---------------- init ----------------

__global__ __launch_bounds__(256) void gather_kernel(const float* __restrict__ emb, const int* __restrict__ ids,
                                                     float* __restrict__ out, int n) {
  int i = blockIdx.x * 256 + threadIdx.x;
  if (i < n * HD) out[i] = emb[(size_t)ids[i >> 6] * HD + (i & 63)];
}

// ---------------- tiled GEMM: out[N,C] = x[N,64] @ W[64,C] + b ----------------
// grid.x = row tiles of 64, grid.y = col tiles of 64. 256 threads, 4x4 micro-tile.
__global__ __launch_bounds__(256) void gemm64_kernel(const float* __restrict__ x,
    const float* __restrict__ W, const float* __restrict__ b,
    float* __restrict__ out, int N, int C) {
  __shared__ float Xt[64][68];   // Xt[k][row], +4 pad keeps float4 alignment & spreads banks
  __shared__ float Wl[64][68];   // Wl[k][col]
  __shared__ float bias[64];
  int t = threadIdx.x;
  int rbase = blockIdx.x * 64;
  int cbase = blockIdx.y * 64;
#pragma unroll
  for (int i = 0; i < 4; ++i) {
    int slot = i * 256 + t;        // 1024 float4 slots of the 64x64 X tile
    int row = slot >> 4;
    int k4 = slot & 15;
    float4 xv = make_float4(0.f, 0.f, 0.f, 0.f);
    if (rbase + row < N) xv = *(const float4*)&x[(size_t)(rbase + row) * 64 + k4 * 4];
    Xt[k4 * 4 + 0][row] = xv.x;
    Xt[k4 * 4 + 1][row] = xv.y;
    Xt[k4 * 4 + 2][row] = xv.z;
    Xt[k4 * 4 + 3][row] = xv.w;
  }
#pragma unroll
  for (int i = 0; i < 4; ++i) {
    int slot = i * 256 + t;
    int kk = slot >> 4;
    int c4 = slot & 15;
    float4 wv = *(const float4*)&W[(size_t)kk * C + cbase + c4 * 4];
    *(float4*)&Wl[kk][c4 * 4] = wv;
  }
  if (t < 64) bias[t] = b[cbase + t];
  __syncthreads();

  int c0 = (t & 15) * 4;
  int r0 = (t >> 4) * 4;
  float acc[4][4];
#pragma unroll
  for (int i = 0; i < 4; ++i)
#pragma unroll
    for (int j = 0; j < 4; ++j) acc[i][j] = 0.f;

#pragma unroll 8
  for (int kk = 0; kk < 64; ++kk) {
    float4 xv = *(const float4*)&Xt[kk][r0];
    float4 wv = *(const float4*)&Wl[kk][c0];
    float xr[4] = {xv.x, xv.y, xv.z, xv.w};
    float wc[4] = {wv.x, wv.y, wv.z, wv.w};
#pragma unroll
    for (int i = 0; i < 4; ++i)
#pragma unroll
      for (int j = 0; j < 4; ++j) acc[i][j] = fmaf(xr[i], wc[j], acc[i][j]);
  }

#pragma unroll
  for (int i = 0; i < 4; ++i) {
    int row = rbase + r0 + i;
    if (row < N) {
      float4 o;
      o.x = acc[i][0] + bias[c0 + 0];
      o.y = acc[i][1] + bias[c0 + 1];
      o.z = acc[i][2] + bias[c0 + 2];
      o.w = acc[i][3] + bias[c0 + 3];
      *(float4*)&out[(size_t)row * C + cbase + c0] = o;
    }
  }
}

// ---------------- attention aggregation ----------------
// one block per destination node; wave h = head h; lane = feature dim.
// online softmax over in-edges via CSR; epilogue: head-mean + precomputed skip (+bias) + relu.
// sk and xout may alias (skip was GEMM'd into xout beforehand).
__global__ __launch_bounds__(256) void agg_kernel(const float* __restrict__ q, const float* __restrict__ k,
    const float* __restrict__ v, const int* __restrict__ rowptr, const int* __restrict__ eids,
    const float* __restrict__ sk, float* __restrict__ xout, int relu) {
  int node = blockIdx.x;
  int t = threadIdx.x;
  int h = t >> 6, lane = t & 63;
  __shared__ float headout[NH][HD];
  float qv = q[(size_t)node * QK + h * HD + lane];
  int beg = rowptr[node], end = rowptr[node + 1];
  float m = -1e30f, lsum = 0.f, acc = 0.f;
  for (int e = beg; e < end; ++e) {
    int src = eids[e];
    float kk = k[(size_t)src * QK + h * HD + lane];
    float vv = v[(size_t)src * QK + h * HD + lane];
    float s = qv * kk;
#pragma unroll
    for (int o = 32; o > 0; o >>= 1) s += __shfl_xor(s, o, 64);
    s *= 0.125f;  // 1/sqrt(64)
    float mn = fmaxf(m, s);
    float sc = __expf(m - mn);
    float w = __expf(s - mn);
    lsum = lsum * sc + w;
    acc = acc * sc + w * vv;
    m = mn;
  }
  headout[h][lane] = (lsum > 0.f) ? acc / lsum : 0.f;
  __syncthreads();
  if (t < HD) {
    float r = 0.25f * (headout[0][t] + headout[1][t] + headout[2][t] + headout[3][t]) +
              sk[(size_t)node * HD + t];
    if (relu) r = fmaxf(r, 0.f);
    xout[(size_t)node * HD + t] = r;
  }
}

// ---------------- classifier ----------------
__global__ __launch_bounds__(256) void classifier_kernel(const float* __restrict__ xs, const float* __restrict__ xt,
    const int* __restrict__ ls, const int* __restrict__ lt, float* __restrict__ out, int n) {
  int g = blockIdx.x * 256 + threadIdx.x;
  int w = g >> 6, lane = g & 63;
  if (w >= n) return;
  float a = xs[(size_t)ls[w] * HD + lane] * xt[(size_t)lt[w] * HD + lane];
#pragma unroll
  for (int o = 32; o > 0; o >>= 1) a += __shfl_xor(a, o, 64);
  if (lane == 0) out[w] = a;
}

// ---------------- launch ----------------
extern "C" void kernel_launch(void* const* d_in, const int* in_sizes, int n_in,
                              void* d_out, int out_size, void* d_ws, size_t ws_size,
                              hipStream_t stream) {
  const float* src_emb = (const float*)d_in[0];
  const float* tgt_emb = (const float*)d_in[1];
  const float* Wq = (const float*)d_in[2];
  const float* bq = (const float*)d_in[3];
  const float* Wk = (const float*)d_in[4];
  const float* bk = (const float*)d_in[5];
  const float* Wv = (const float*)d_in[6];
  const float* bv = (const float*)d_in[7];
  const float* Wsk = (const float*)d_in[8];
  const float* bsk = (const float*)d_in[9];
  const int* nid_s = (const int*)d_in[10];
  const int* nid_t = (const int*)d_in[11];
  const int* e_st = (const int*)d_in[12];
  const int* e_ts = (const int*)d_in[13];
  const int* e_lbl = (const int*)d_in[14];
  float* out = (float*)d_out;

  char* ws = (char*)d_ws;
  size_t off = 0;
  auto alloc = [&](size_t bytes) -> void* {
    void* p = ws + off;
    off += (bytes + 255) & ~(size_t)255;
    return p;
  };
  float* big1   = (float*)alloc((size_t)NSRC * QK * 4);   // st: k | ts: q
  float* big2   = (float*)alloc((size_t)NSRC * QK * 4);   // st: v
  float* small1 = (float*)alloc((size_t)NTGT * QK * 4);   // st: q | ts: k
  float* small2 = (float*)alloc((size_t)NTGT * QK * 4);   // ts: v
  float* xsA = (float*)alloc((size_t)NSRC * HD * 4);
  float* xsB = (float*)alloc((size_t)NSRC * HD * 4);
  float* xtA = (float*)alloc((size_t)NTGT * HD * 4);
  float* xtB = (float*)alloc((size_t)NTGT * HD * 4);
  int* rp_st = (int*)alloc((size_t)(NTGT + 1) * 4);
  int* ei_st = (int*)alloc((size_t)NEDGE * 4);
  int* rp_ts = (int*)alloc((size_t)(NSRC + 1) * 4);
  int* ei_ts = (int*)alloc((size_t)NEDGE * 4);
  int* cursor = (int*)alloc((size_t)(NSRC + 1) * 4);
  int* counts = (int*)alloc((size_t)(NSRC + 1) * 4);
  (void)ws_size; (void)in_sizes; (void)n_in; (void)out_size;

  auto cdiv = [](int a, int b) { return (a + b - 1) / b; };
  const int RT_S = cdiv(NSRC, 64);   // 782 row tiles
  const int RT_T = cdiv(NTGT, 64);   // 157

  // CSR st: segment by target (row1 of e_st), payload = source id (row0)
  zero_int_kernel<<<cdiv(NTGT, 256), 256, 0, stream>>>(counts, NTGT);
  hist_kernel<<<cdiv(NEDGE, 256), 256, 0, stream>>>(e_st + NEDGE, counts, NEDGE);
  scan_kernel<<<1, 1024, 0, stream>>>(counts, rp_st, NTGT);
  copy_int_kernel<<<cdiv(NTGT, 256), 256, 0, stream>>>(rp_st, cursor, NTGT);
  scatter_kernel<<<cdiv(NEDGE, 256), 256, 0, stream>>>(e_st, e_st + NEDGE, cursor, ei_st, NEDGE);

  // CSR ts: segment by source node (row1 of e_ts), payload = target id (row0)
  zero_int_kernel<<<cdiv(NSRC, 256), 256, 0, stream>>>(counts, NSRC);
  hist_kernel<<<cdiv(NEDGE, 256), 256, 0, stream>>>(e_ts + NEDGE, counts, NEDGE);
  scan_kernel<<<1, 1024, 0, stream>>>(counts, rp_ts, NSRC);
  copy_int_kernel<<<cdiv(NSRC, 256), 256, 0, stream>>>(rp_ts, cursor, NSRC);
  scatter_kernel<<<cdiv(NEDGE, 256), 256, 0, stream>>>(e_ts, e_ts + NEDGE, cursor, ei_ts, NEDGE);

  // initial node features
  gather_kernel<<<cdiv(NSRC * HD, 256), 256, 0, stream>>>(src_emb, nid_s, xsA, NSRC);
  gather_kernel<<<cdiv(NTGT * HD, 256), 256, 0, stream>>>(tgt_emb, nid_t, xtA, NTGT);

  const float* xs_cur = xsA; float* xs_nxt = xsB;
  const float* xt_cur = xtA; float* xt_nxt = xtB;
  for (int l = 0; l < 2; ++l) {
    int relu = (l == 0) ? 1 : 0;
    {  // source->target conv (et=0): updates target nodes
      int p = l * 2 + 0;
      gemm64_kernel<<<dim3(RT_S, 4), 256, 0, stream>>>(xs_cur, Wk + p * 16384, bk + p * 256, big1, NSRC, QK);
      gemm64_kernel<<<dim3(RT_S, 4), 256, 0, stream>>>(xs_cur, Wv + p * 16384, bv + p * 256, big2, NSRC, QK);
      gemm64_kernel<<<dim3(RT_T, 4), 256, 0, stream>>>(xt_cur, Wq + p * 16384, bq + p * 256, small1, NTGT, QK);
      gemm64_kernel<<<dim3(RT_T, 1), 256, 0, stream>>>(xt_cur, Wsk + p * 4096, bsk + p * 64, xt_nxt, NTGT, HD);
      agg_kernel<<<NTGT, 256, 0, stream>>>(small1, big1, big2, rp_st, ei_st, xt_nxt, xt_nxt, relu);
    }
    {  // target->source conv (et=1): updates source nodes
      int p = l * 2 + 1;
      gemm64_kernel<<<dim3(RT_T, 4), 256, 0, stream>>>(xt_cur, Wk + p * 16384, bk + p * 256, small1, NTGT, QK);
      gemm64_kernel<<<dim3(RT_T, 4), 256, 0, stream>>>(xt_cur, Wv + p * 16384, bv + p * 256, small2, NTGT, QK);
      gemm64_kernel<<<dim3(RT_S, 4), 256, 0, stream>>>(xs_cur, Wq + p * 16384, bq + p * 256, big1, NSRC, QK);
      gemm64_kernel<<<dim3(RT_S, 1), 256, 0, stream>>>(xs_cur, Wsk + p * 4096, bsk + p * 64, xs_nxt, NSRC, HD);
      agg_kernel<<<NSRC, 256, 0, stream>>>(big1, small1, small2, rp_ts, ei_ts, xs_nxt, xs_nxt, relu);
    }
    const float* t0 = xs_nxt; xs_nxt = (float*)xs_cur; xs_cur = t0;
    const float* t1 = xt_nxt; xt_nxt = (float*)xt_cur; xt_cur = t1;
  }

  classifier_kernel<<<cdiv(NLBL, 4), 256, 0, stream>>>(xs_cur, xt_cur, e_lbl, e_lbl + NLBL, out, NLBL);
}